// Round 1
// baseline (1960.395 us; speedup 1.0000x reference)
//
#include <hip/hip_runtime.h>
#include <math.h>

// Problem constants (from reference)
#define NG   1024        // graphs (blocks)
#define NP   256         // nodes per graph
#define EPG  4096        // edges per graph
#define ETOT 4194304     // total edges
#define FIN  7
#define HD   64
#define KC   50
#define SST  52          // padded row stride for S / AS (16B-aligned rows, pads = 0)
#define NTH  512
#define NWAVE 8

__global__ void zero_ws(float* ws) {
    if (threadIdx.x < 2) ws[threadIdx.x] = 0.f;
}

__global__ void finalize_k(const float* __restrict__ ws, float* __restrict__ out) {
    if (threadIdx.x == 0) {
        float link = sqrtf(fmaxf(ws[0], 0.f)) / 67108864.0f;  // / A.size = 1024*256*256
        float ent  = -ws[1] / 262144.0f;                      // / N
        out[2048] = link + ent;
    }
}

__device__ __forceinline__ float blockReduce(float v, float* red) {
    __syncthreads();   // protect red from previous use
    #pragma unroll
    for (int o = 32; o > 0; o >>= 1) v += __shfl_down(v, o);
    if ((threadIdx.x & 63) == 0) red[threadIdx.x >> 6] = v;
    __syncthreads();
    float r = (threadIdx.x < NWAVE) ? red[threadIdx.x] : 0.f;
    #pragma unroll
    for (int o = 4; o > 0; o >>= 1) r += __shfl_down(r, o);
    return r;   // valid on thread 0
}

// One workgroup per graph. 8 waves. ~150 KB LDS -> 1 block/CU, 2 waves/SIMD.
__launch_bounds__(NTH, 2)
__global__ void graph_k(
    const float* __restrict__ x,
    const float* __restrict__ W1a, const float* __restrict__ b1a,
    const float* __restrict__ W1b, const float* __restrict__ b1b,
    const float* __restrict__ Wp,  const float* __restrict__ bp,
    const float* __restrict__ W2a, const float* __restrict__ b2a,
    const float* __restrict__ W2b, const float* __restrict__ b2b,
    const float* __restrict__ Wl,  const float* __restrict__ bl,
    const int* __restrict__ esrc,  const int* __restrict__ edst,
    float* __restrict__ out, float* __restrict__ ws)
{
    // u1: A-count chunks -> t1/h tile (in-place) -> AS (stride 52)
    __shared__ __align__(16) union { unsigned int cnt[16384]; float f[16384]; } u1;
    // u2: x|agg -> S (stride 52) -> h2 | t
    __shared__ __align__(16) float u2f[NP * SST];
    __shared__ __align__(16) float PT[HD * KC];      // xp transposed: PT[d][k]
    __shared__ __align__(16) float ApBuf[KC * KC];   // G, then Ap
    __shared__ __align__(16) unsigned short cells[EPG];
    __shared__ float red[NWAVE];

    const int g = blockIdx.x, tid = threadIdx.x;
    const int lane = tid & 63, wid = tid >> 6;
    const int kk = (lane < KC) ? lane : (KC - 1);   // clamped k index for k-lane phases

    float sumA2 = 0.f, entL = 0.f, sumSSt2 = 0.f, sumASSt = 0.f, l0 = 0.f, l1 = 0.f;

    // ---- P0: stage edges (packed local cells), x tile; zero agg/PT/ApBuf ----
    for (int e = tid; e < EPG; e += NTH) {
        int s = esrc[g * EPG + e] & (NP - 1);
        int d = edst[g * EPG + e] & (NP - 1);
        cells[e] = (unsigned short)((s << 8) | d);
    }
    for (int i = tid; i < NP * FIN; i += NTH) {
        u2f[i] = x[g * NP * FIN + i];   // x tile
        u2f[NP * FIN + i] = 0.f;        // agg
    }
    for (int i = tid; i < HD * KC; i += NTH) PT[i] = 0.f;
    for (int i = tid; i < KC * KC; i += NTH) ApBuf[i] = 0.f;
    __syncthreads();

    // ---- P1: sum(A^2) exactly, via chunked dense counts (4 x 16384 cells) ----
    for (int ch = 0; ch < 4; ++ch) {
        for (int i = tid; i < 16384; i += NTH) u1.cnt[i] = 0u;
        __syncthreads();
        int base = ch << 14;
        for (int e = tid; e < EPG; e += NTH) {
            int r = (int)cells[e] - base;
            if ((unsigned)r < 16384u) atomicAdd(&u1.cnt[r], 1u);
        }
        __syncthreads();
        for (int i = tid; i < 16384; i += NTH) { float m = (float)u1.cnt[i]; sumA2 += m * m; }
        __syncthreads();
    }

    // ---- P2: GIN aggregation: agg[di] += x[si] over edges ----
    for (int e = tid; e < EPG; e += NTH) {
        int c = cells[e]; int si = c >> 8, di = c & 255;
        #pragma unroll
        for (int f = 0; f < FIN; ++f)
            atomicAdd(&u2f[NP * FIN + di * FIN + f], u2f[si * FIN + f]);
    }
    __syncthreads();

    // ---- P3a: t1 = relu((x+agg) @ W1a + b1a)  -> u1.f[n*64+lane] ----
    {
        float w1r[FIN];
        #pragma unroll
        for (int f = 0; f < FIN; ++f) w1r[f] = W1a[f * HD + lane];
        float br = b1a[lane];
        for (int n = wid; n < NP; n += NWAVE) {
            float a = br;
            #pragma unroll
            for (int f = 0; f < FIN; ++f)
                a += (u2f[n * FIN + f] + u2f[NP * FIN + n * FIN + f]) * w1r[f];
            u1.f[n * HD + lane] = fmaxf(a, 0.f);
        }
    }
    __syncthreads();

    // ---- P3b: h = t1 @ W1b + b1b (in-place per row; rows private to a wave) ----
    {
        float wr[HD];
        #pragma unroll
        for (int j = 0; j < HD; ++j) wr[j] = W1b[j * HD + lane];
        float br = b1b[lane];
        for (int n = wid; n < NP; n += NWAVE) {
            float a0 = br, a1 = 0.f, a2 = 0.f, a3 = 0.f;
            const float4* t4 = (const float4*)&u1.f[n * HD];
            #pragma unroll
            for (int i = 0; i < 16; ++i) {
                float4 v = t4[i];
                a0 += v.x * wr[4*i]; a1 += v.y * wr[4*i+1];
                a2 += v.z * wr[4*i+2]; a3 += v.w * wr[4*i+3];
            }
            u1.f[n * HD + lane] = (a0 + a1) + (a2 + a3);
        }
    }
    __syncthreads();

    // ---- P4: S = softmax(h @ Wp + bp); entropy partial; S stride 52, pads=0 ----
    {
        float wr[HD];
        #pragma unroll
        for (int j = 0; j < HD; ++j) wr[j] = Wp[j * KC + kk];
        float br = bp[kk];
        for (int n = wid; n < NP; n += NWAVE) {
            float a0 = br, a1 = 0.f, a2 = 0.f, a3 = 0.f;
            const float4* h4 = (const float4*)&u1.f[n * HD];
            #pragma unroll
            for (int i = 0; i < 16; ++i) {
                float4 v = h4[i];
                a0 += v.x * wr[4*i]; a1 += v.y * wr[4*i+1];
                a2 += v.z * wr[4*i+2]; a3 += v.w * wr[4*i+3];
            }
            float a = (a0 + a1) + (a2 + a3);
            if (lane >= KC) a = -INFINITY;
            float m = a;
            #pragma unroll
            for (int o = 32; o > 0; o >>= 1) m = fmaxf(m, __shfl_xor(m, o));
            float e = expf(a - m);          // lanes >= KC -> 0
            float ss = e;
            #pragma unroll
            for (int o = 32; o > 0; o >>= 1) ss += __shfl_xor(ss, o);
            float s = e / ss;
            if (lane < SST) u2f[n * SST + lane] = s;   // pads (50,51) get 0
            if (lane < KC) entL += s * logf(s + 1e-15f);
        }
    }
    __syncthreads();

    // ---- P5: waves 0-3: xp = S^T h (reg-accumulated, atomic into PT)
    //          waves 4-7: G = S^T S (atomic into ApBuf) ----
    if (wid < 4) {
        float acc[HD];
        #pragma unroll
        for (int c = 0; c < HD; ++c) acc[c] = 0.f;
        int n0 = wid * 64;
        for (int n = n0; n < n0 + 64; ++n) {
            float sk = u2f[n * SST + kk];
            const float4* h4 = (const float4*)&u1.f[n * HD];
            #pragma unroll
            for (int i = 0; i < 16; ++i) {
                float4 v = h4[i];
                acc[4*i]   += sk * v.x; acc[4*i+1] += sk * v.y;
                acc[4*i+2] += sk * v.z; acc[4*i+3] += sk * v.w;
            }
        }
        if (lane < KC) {
            #pragma unroll
            for (int c = 0; c < HD; ++c) atomicAdd(&PT[c * KC + lane], acc[c]);
        }
    } else {
        float acc[SST];
        #pragma unroll
        for (int c = 0; c < SST; ++c) acc[c] = 0.f;
        int n0 = (wid - 4) * 64;
        for (int n = n0; n < n0 + 64; ++n) {
            float sk = u2f[n * SST + kk];
            const float4* s4 = (const float4*)&u2f[n * SST];
            #pragma unroll
            for (int i = 0; i < 13; ++i) {
                float4 v = s4[i];
                acc[4*i]   += sk * v.x; acc[4*i+1] += sk * v.y;
                acc[4*i+2] += sk * v.z; acc[4*i+3] += sk * v.w;
            }
        }
        if (lane < KC) {
            #pragma unroll
            for (int c = 0; c < KC; ++c) atomicAdd(&ApBuf[lane * KC + c], acc[c]);
        }
    }
    __syncthreads();

    // ---- P6a: sumSSt2 = ||G||_F^2 ; zero AS region (h is dead) ----
    for (int i = tid; i < KC * KC; i += NTH) { float v = ApBuf[i]; sumSSt2 += v * v; }
    for (int i = tid; i < NP * SST; i += NTH) u1.f[i] = 0.f;
    __syncthreads();

    // ---- P6b: zero ApBuf for Ap; AS scatter AS[si,:] += S[di,:] (lanes = k) ----
    for (int i = tid; i < KC * KC; i += NTH) ApBuf[i] = 0.f;
    for (int e = wid; e < EPG; e += NWAVE) {
        int c = cells[e]; int si = c >> 8, di = c & 255;
        float sv = u2f[di * SST + kk];
        if (lane < KC) atomicAdd(&u1.f[si * SST + lane], sv);
    }
    __syncthreads();

    // ---- P8: sumASSt = sum(AS .* S); Ap = S^T AS (atomic into ApBuf) ----
    {
        float ap[SST];
        #pragma unroll
        for (int c = 0; c < SST; ++c) ap[c] = 0.f;
        int n0 = wid * 32;
        for (int n = n0; n < n0 + 32; ++n) {
            float sk = u2f[n * SST + kk];
            if (lane < KC) sumASSt += sk * u1.f[n * SST + kk];
            const float4* a4 = (const float4*)&u1.f[n * SST];
            #pragma unroll
            for (int i = 0; i < 13; ++i) {
                float4 v = a4[i];
                ap[4*i]   += sk * v.x; ap[4*i+1] += sk * v.y;
                ap[4*i+2] += sk * v.z; ap[4*i+3] += sk * v.w;
            }
        }
        if (lane < KC) {
            #pragma unroll
            for (int c = 0; c < KC; ++c) atomicAdd(&ApBuf[lane * KC + c], ap[c]);
        }
    }
    __syncthreads();

    // ---- P9: h2 = xp + Ap @ xp  -> u2f[k*64+d] (S is dead) ----
    for (int k = wid; k < KC; k += NWAVE) {
        float a = PT[lane * KC + k];
        #pragma unroll
        for (int l = 0; l < KC; ++l)
            a += ApBuf[k * KC + l] * PT[lane * KC + l];
        u2f[k * HD + lane] = a;
    }
    __syncthreads();

    // ---- P10: t = relu(h2 @ W2a + b2a) -> u2f[KC*HD + ...] ----
    {
        float wr[HD];
        #pragma unroll
        for (int d = 0; d < HD; ++d) wr[d] = W2a[d * HD + lane];
        float br = b2a[lane];
        for (int k = wid; k < KC; k += NWAVE) {
            float a0 = br, a1 = 0.f, a2 = 0.f, a3 = 0.f;
            const float4* h4 = (const float4*)&u2f[k * HD];
            #pragma unroll
            for (int i = 0; i < 16; ++i) {
                float4 v = h4[i];
                a0 += v.x * wr[4*i]; a1 += v.y * wr[4*i+1];
                a2 += v.z * wr[4*i+2]; a3 += v.w * wr[4*i+3];
            }
            u2f[KC * HD + k * HD + lane] = fmaxf((a0 + a1) + (a2 + a3), 0.f);
        }
    }
    __syncthreads();

    // ---- P11: h3 = t @ W2b + b2b; fold mean over k and Wl into l0/l1 partials ----
    {
        float wr[HD];
        #pragma unroll
        for (int j = 0; j < HD; ++j) wr[j] = W2b[j * HD + lane];
        float br = b2b[lane];
        float wl0 = Wl[lane * 2], wl1 = Wl[lane * 2 + 1];
        for (int k = wid; k < KC; k += NWAVE) {
            float a0 = br, a1 = 0.f, a2 = 0.f, a3 = 0.f;
            const float4* t4 = (const float4*)&u2f[KC * HD + k * HD];
            #pragma unroll
            for (int i = 0; i < 16; ++i) {
                float4 v = t4[i];
                a0 += v.x * wr[4*i]; a1 += v.y * wr[4*i+1];
                a2 += v.z * wr[4*i+2]; a3 += v.w * wr[4*i+3];
            }
            float a = (a0 + a1) + (a2 + a3);
            l0 += a * wl0; l1 += a * wl1;
        }
    }

    // ---- P12: block reductions, loss atomics, per-graph log_softmax ----
    float rA2   = blockReduce(sumA2, red);
    float rASSt = blockReduce(sumASSt, red);
    float rSSt2 = blockReduce(sumSSt2, red);
    float rEnt  = blockReduce(entL, red);
    float rl0   = blockReduce(l0, red);
    float rl1   = blockReduce(l1, red);
    if (tid == 0) {
        atomicAdd(&ws[0], rA2 - 2.f * rASSt + rSSt2);
        atomicAdd(&ws[1], rEnt);
        float g0 = bl[0] + rl0 * (1.f / KC);
        float g1 = bl[1] + rl1 * (1.f / KC);
        float mm = fmaxf(g0, g1);
        float lse = mm + logf(expf(g0 - mm) + expf(g1 - mm));
        out[2 * g]     = g0 - lse;
        out[2 * g + 1] = g1 - lse;
    }
}

extern "C" void kernel_launch(void* const* d_in, const int* in_sizes, int n_in,
                              void* d_out, int out_size, void* d_ws, size_t ws_size,
                              hipStream_t stream) {
    const float* x    = (const float*)d_in[0];
    const float* W1a  = (const float*)d_in[1];
    const float* b1a  = (const float*)d_in[2];
    const float* W1b  = (const float*)d_in[3];
    const float* b1b  = (const float*)d_in[4];
    const float* Wp   = (const float*)d_in[5];
    const float* bp   = (const float*)d_in[6];
    const float* W2a  = (const float*)d_in[7];
    const float* b2a  = (const float*)d_in[8];
    const float* W2b  = (const float*)d_in[9];
    const float* b2b  = (const float*)d_in[10];
    const float* Wl   = (const float*)d_in[11];
    const float* bl   = (const float*)d_in[12];
    const int*   eidx = (const int*)d_in[13];   // [2, E] int32
    // d_in[14] (batch) unused: graphs are contiguous equal-size blocks
    float* out = (float*)d_out;
    float* ws  = (float*)d_ws;

    zero_ws<<<1, 64, 0, stream>>>(ws);
    graph_k<<<NG, NTH, 0, stream>>>(x, W1a, b1a, W1b, b1b, Wp, bp,
                                    W2a, b2a, W2b, b2b, Wl, bl,
                                    eidx, eidx + ETOT, out, ws);
    finalize_k<<<1, 64, 0, stream>>>(ws, out);
}